// Round 1
// baseline (485.718 us; speedup 1.0000x reference)
//
#include <hip/hip_runtime.h>
#include <hip/hip_cooperative_groups.h>
#include <stdint.h>
#include <math.h>

namespace cg = cooperative_groups;

typedef unsigned long long u64;
typedef unsigned int u32;

#define NPI   360000
#define B_IMG 8
#define PRE   1000
#define POST  300
#define CAP   4096
#define NMSF  0.7f
#define IMG_W 800.0f
#define IMG_H 800.0f

#define NBIN    8192          // 13-bit sortable-key histogram
#define KSHIFT  19            // fkey >> 19 -> 13-bit bin
#define CHUNK_H 36            // hist units per image (divides 90000)
#define F4PB_H  (NPI / 4 / CHUNK_H)   // 2500
#define CHUNK_C 48            // compact units per image
#define F4PB_C  (NPI / 4 / CHUNK_C)   // 1875
#define EPB_C   (NPI / CHUNK_C)       // 7500
#define LBUF    1024          // per-block candidate buffer

// ---- workspace layout (bytes) ----
#define CNT_OFF    0          // 8*4
#define THRESH_OFF 128        // 8*4
#define VALID_OFF  256        // 8*16*8 = 1024      -> 1280
#define RHIST_OFF  4096       // 8*8192*4 = 262144  -> 266240
#define ZERO_BYTES 266240     // cnt+thresh+validw+rhist (fallback path only)
#define BOX_OFF    266240     // 8*1000*16 = 128000 -> 394240
#define SCORE_OFF  394240     // 8*1000*4 = 32000   -> 426240
#define CAND_OFF   426240     // 8*4096*8 = 262144  -> 688384
#define MASK_OFF   688384     // 8*1000*16*8 = 1024000 -> 1712384

#define LDSROWS 496
#define NMS_T   320           // fallback k_nms block size
#define FGRID   256           // fused kernel grid (1 block/CU guaranteed co-resident)

__device__ __forceinline__ u32 fkey(float f) {
  u32 u = __float_as_uint(f);
  return (u & 0x80000000u) ? ~u : (u | 0x80000000u);  // ascending-order bits
}
__device__ __forceinline__ u64 rl64(u64 v, int lane) {
  u32 lo = (u32)__builtin_amdgcn_readlane((int)(u32)v, lane);
  u32 hi = (u32)__builtin_amdgcn_readlane((int)(u32)(v >> 32), lane);
  return ((u64)hi << 32) | lo;
}
__device__ __forceinline__ u64 sx64(u64 v, int m) {
  u32 lo = (u32)__shfl_xor((int)(u32)v, m, 64);
  u32 hi = (u32)__shfl_xor((int)(u32)(v >> 32), m, 64);
  return ((u64)hi << 32) | lo;
}

// decode/clip one ranked candidate into its output row (numerics identical to ref)
__device__ __forceinline__ void emit_row(
    int img, int row, u64 key,
    const float* __restrict__ deltas, const float* __restrict__ anchors,
    float4* __restrict__ boxes, float* __restrict__ scores, u64* __restrict__ validw) {
  u32 hi  = (u32)(key >> 32);
  u32 idx = 0xFFFFFFFFu - (u32)(key & 0xFFFFFFFFu);
  u32 su  = (hi & 0x80000000u) ? (hi ^ 0x80000000u) : ~hi;
  float sc = __uint_as_float(su);
  size_t off = (size_t)img * NPI + idx;
  float4 d = ((const float4*)deltas)[off];
  float4 a = ((const float4*)anchors)[off];
  float aw = a.z - a.x, ah = a.w - a.y;
  float acx = a.x + 0.5f * aw, acy = a.y + 0.5f * ah;
  float cx = d.x * aw + acx, cy = d.y * ah + acy;
  float w = expf(d.z) * aw, h = expf(d.w) * ah;
  float x1 = cx - 0.5f * w, y1 = cy - 0.5f * h;
  float x2 = cx + 0.5f * w, y2 = cy + 0.5f * h;
  x1 = fminf(fmaxf(x1, 0.f), IMG_W);
  y1 = fminf(fmaxf(y1, 0.f), IMG_H);
  x2 = fminf(fmaxf(x2, 0.f), IMG_W);
  y2 = fminf(fmaxf(y2, 0.f), IMG_H);
  boxes[img * PRE + row]  = make_float4(x1, y1, x2, y2);
  scores[img * PRE + row] = sc;
  if (((x2 - x1) >= 1e-3f) && ((y2 - y1) >= 1e-3f))
    atomicOr(&validw[img * 16 + (row >> 6)], 1ull << (row & 63));
}

// ================== FUSED COOPERATIVE PIPELINE ==================
// One dispatch; 6 grid.sync()s replace 6 kernel boundaries (~25 us each).
__global__ __launch_bounds__(256) void k_fused(
    const float* __restrict__ logits, const float* __restrict__ deltas,
    const float* __restrict__ anchors,
    u32* __restrict__ cnt, int* __restrict__ thresh, u64* __restrict__ validw,
    u32* __restrict__ rhist, float4* __restrict__ boxes, float* __restrict__ scores,
    u64* __restrict__ cand, u64* __restrict__ mask, float* __restrict__ out) {
  __shared__ union {
    u32 hist[NBIN];                                            // 32 KB  (stage 1)
    u32 wtot[4];                                               //        (stage 2)
    struct { u64 buf[LBUF]; u32 bcnt; u32 gbase; } comp;       // 8.2 KB (stage 3)
    u64 skey[CAP];                                             // 32 KB  (stage 4)
    struct { float4 sb[1024]; float sa[1024]; } iou;           // 20 KB  (stage 5)
    struct { u64 smask[LDSROWS * 16]; int keeplist[POST]; int kept; } nms; // 64.7 KB
  } lds;
  cg::grid_group grid = cg::this_grid();
  const int bid = blockIdx.x, tid = threadIdx.x;

  // ---- stage 0: zero accumulators (replaces hipMemsetAsync dispatch) ----
  {
    int g = bid * 256 + tid;          // 65536 threads == 8*8192 rhist words
    rhist[g] = 0;
    if (g < B_IMG) cnt[g] = 0;
    if (g < B_IMG * 16) validw[g] = 0;
  }
  __threadfence();
  grid.sync();

  // ---- stage 1: per-(image,chunk) LDS histogram; flush nonzero bins ----
  for (int u = bid; u < B_IMG * CHUNK_H; u += FGRID) {
    const int img = u / CHUNK_H, c = u % CHUNK_H;
    for (int i = tid; i < NBIN; i += 256) lds.hist[i] = 0;
    __syncthreads();
    const float4* L = (const float4*)(logits + (size_t)img * NPI) + (size_t)c * F4PB_H;
    for (int i = tid; i < F4PB_H; i += 256) {
      float4 v = L[i];
      atomicAdd(&lds.hist[fkey(v.x) >> KSHIFT], 1u);
      atomicAdd(&lds.hist[fkey(v.y) >> KSHIFT], 1u);
      atomicAdd(&lds.hist[fkey(v.z) >> KSHIFT], 1u);
      atomicAdd(&lds.hist[fkey(v.w) >> KSHIFT], 1u);
    }
    __syncthreads();
    u32* R = rhist + img * NBIN;
    for (int i = tid; i < NBIN; i += 256) {
      u32 cv = lds.hist[i];
      if (cv) atomicAdd(&R[i], cv);
    }
    __syncthreads();
  }
  __threadfence();
  grid.sync();

  // ---- stage 2: threshold select (blocks 0..7, 256 thr, 32 bins/thread) ----
  if (bid < B_IMG) {
    const int img = bid, t = tid;
    const int lane = t & 63, w = t >> 6;      // 4 waves
    const uint4* H4 = (const uint4*)(rhist + img * NBIN);
    u32 binc[32];
    u32 s = 0;
#pragma unroll
    for (int q = 0; q < 8; q++) {
      uint4 v = H4[8 * t + q];                // bins [32t .. 32t+32)
      binc[4 * q + 0] = v.x; binc[4 * q + 1] = v.y;
      binc[4 * q + 2] = v.z; binc[4 * q + 3] = v.w;
      s += v.x + v.y + v.z + v.w;
    }
    // wave-level inclusive suffix sum (lane l -> sum over lanes >= l)
    u32 suf = s;
#pragma unroll
    for (int off = 1; off < 64; off <<= 1) {
      u32 o = (u32)__shfl_down((int)suf, off, 64);
      if (lane + off < 64) suf += o;
    }
    if (lane == 0) lds.wtot[w] = suf;
    __syncthreads();
    u32 wsuf = 0;
    for (int ww = w + 1; ww < 4; ww++) wsuf += lds.wtot[ww];
    u32 suffix_incl = suf + wsuf;             // count over groups >= t
    u32 s_excl = suffix_incl - s;             // count over groups > t
    if (suffix_incl >= (u32)PRE && s_excl < (u32)PRE) {
      u32 cum = s_excl;
      int bin = 32 * t;
#pragma unroll
      for (int b = 31; b >= 0; b--) {
        cum += binc[b];
        if (cum >= (u32)PRE) { bin = 32 * t + b; break; }
      }
      thresh[img] = bin;
    }
  }
  __threadfence();
  grid.sync();

  // ---- stage 3: compact candidates >= threshold bin ----
  for (int u = bid; u < B_IMG * CHUNK_C; u += FGRID) {
    const int img = u / CHUNK_C, c = u % CHUNK_C;
    const int tb = thresh[img];
    if (tid == 0) lds.comp.bcnt = 0;
    __syncthreads();
    const float4* L = (const float4*)(logits + (size_t)img * NPI) + (size_t)c * F4PB_C;
    const int ebase = c * EPB_C;
    for (int i = tid; i < F4PB_C; i += 256) {
      float4 v = L[i];
      float xs[4] = {v.x, v.y, v.z, v.w};
#pragma unroll
      for (int q = 0; q < 4; q++) {
        float x = xs[q];
        if ((int)(fkey(x) >> KSHIFT) >= tb) {
          // fp32 sigmoid with correctly-rounded exp: replicates numpy f32
          // tie structure exactly (verified: absmax 0.0)
          float ef = (float)exp(-(double)x);
          float sg = 1.0f / (1.0f + ef);
          u32 e = (u32)(ebase + 4 * i + q);
          u32 p = atomicAdd(&lds.comp.bcnt, 1u);
          if (p < LBUF)
            lds.comp.buf[p] = ((u64)fkey(sg) << 32) | (u64)(0xFFFFFFFFu - e);
        }
      }
    }
    __syncthreads();
    if (tid == 0) {
      u32 m = lds.comp.bcnt < LBUF ? lds.comp.bcnt : LBUF;
      lds.comp.bcnt = m;
      lds.comp.gbase = atomicAdd(&cnt[img], m);
    }
    __syncthreads();
    const u32 m = lds.comp.bcnt, gb = lds.comp.gbase;
    for (u32 j = tid; j < m; j += 256) {
      u32 pos = gb + j;
      if (pos < CAP) cand[img * CAP + pos] = lds.comp.buf[j];
    }
    __syncthreads();
  }
  __threadfence();
  grid.sync();

  // ---- stage 4: exact rank + decode/clip (blocks 0..31, 4 rows/thread) ----
  if (bid < 4 * B_IMG) {
    const int img = bid >> 2, part = bid & 3;
    int n = (int)cnt[img];
    if (n > CAP) n = CAP;
    for (int i = tid; i < n; i += 256) lds.skey[i] = cand[img * CAP + i];
    __syncthreads();
    if (part * 1024 < n) {
      const int r0 = part * 1024 + tid;
      const int r1 = r0 + 256, r2 = r0 + 512, r3 = r0 + 768;
      u64 k0 = (r0 < n) ? lds.skey[r0] : 0ull;
      u64 k1 = (r1 < n) ? lds.skey[r1] : 0ull;
      u64 k2 = (r2 < n) ? lds.skey[r2] : 0ull;
      u64 k3 = (r3 < n) ? lds.skey[r3] : 0ull;
      int c0 = 0, c1 = 0, c2 = 0, c3 = 0;
      for (int j = 0; j < n; j++) {
        u64 kj = lds.skey[j];               // same address across lanes -> broadcast
        c0 += (kj > k0); c1 += (kj > k1); c2 += (kj > k2); c3 += (kj > k3);
      }
      if (r0 < n && c0 < PRE) emit_row(img, c0, k0, deltas, anchors, boxes, scores, validw);
      if (r1 < n && c1 < PRE) emit_row(img, c1, k1, deltas, anchors, boxes, scores, validw);
      if (r2 < n && c2 < PRE) emit_row(img, c2, k2, deltas, anchors, boxes, scores, validw);
      if (r3 < n && c3 < PRE) emit_row(img, c3, k3, deltas, anchors, boxes, scores, validw);
    }
  }
  __threadfence();
  grid.sync();

  // ---- stage 5: suppression bitmask (all 256 blocks: img*32 row-units) ----
  {
    const int img = bid >> 5, rb = bid & 31;    // 32 row-units x 32 rows
    for (int j = tid; j < 1024; j += 256) {
      float4 b = (j < PRE) ? boxes[img * PRE + j] : make_float4(0.f, 0.f, 0.f, 0.f);
      lds.iou.sb[j] = b;
      lds.iou.sa[j] = (b.z - b.x) * (b.w - b.y);
    }
    __syncthreads();
    const int i = rb * 32 + (tid & 31);         // row 0..1023
    const int wq = tid >> 5;                    // 0..7
    const bool rowok = (i < PRE);
    const float4 bi = lds.iou.sb[i];
    const float  ai = lds.iou.sa[i];
#pragma unroll
    for (int hh = 0; hh < 2; hh++) {
      const int wv = wq + 8 * hh;               // word 0..15
      const int cbase = wv << 6;
      u64 bits = 0;
#pragma unroll
      for (int k = 0; k < 64; k++) {
        int c = cbase + k;
        float4 bc = lds.iou.sb[c];              // broadcast read
        float ac  = lds.iou.sa[c];
        float ltx = fmaxf(bi.x, bc.x), lty = fmaxf(bi.y, bc.y);
        float rbx = fminf(bi.z, bc.z), rby = fminf(bi.w, bc.w);
        float iw = fmaxf(rbx - ltx, 0.f), ih = fmaxf(rby - lty, 0.f);
        float inter = iw * ih;
        float iou = inter / (ai + ac - inter + 1e-9f);   // IEEE div, matches ref
        bits |= (iou > NMSF) ? (1ull << k) : 0ull;
      }
      int d = i - cbase;
      u64 gtmask = (d < 0) ? ~0ull : ((d >= 63) ? 0ull : (~0ull << (d + 1)));
      int rem = PRE - cbase;
      u64 tmask = (rem >= 64) ? ~0ull : ((rem <= 0) ? 0ull : ((1ull << rem) - 1ull));
      bits &= gtmask & tmask;
      if (rowok) mask[((size_t)img * PRE + i) * 16 + wv] = bits;
    }
  }
  __threadfence();
  grid.sync();

  // ---- stage 6: chunked greedy NMS scan (blocks 0..7) ----
  if (bid < B_IMG) {
    const int img = bid;
    const u64* M = mask + (size_t)img * PRE * 16;
    u64 diag[16];
    if (tid < 64) {
#pragma unroll
      for (int cc = 0; cc < 16; cc++) {
        int row = cc * 64 + tid;
        diag[cc] = (row < PRE) ? M[(size_t)row * 16 + cc] : 0ull;
      }
    }
    for (int e = tid; e < LDSROWS * 16; e += 256) lds.nms.smask[e] = M[e];
    __syncthreads();
    if (tid < 64) {
      const int lane = tid;
      const int w = lane & 15, g = lane >> 4;
      u64 rem = ~0ull;
      if (lane < 16) {
        rem = ~validw[img * 16 + lane];
        if (lane == 15) rem |= 0xFFFFFF0000000000ull;  // rows 1000..1023 invalid
      }
      int kept = 0;
#pragma unroll
      for (int cc = 0; cc < 16; cc++) {
        u64 alive = ~rl64(rem, cc);        // wave-uniform
        int kept0 = kept;
        while (alive != 0ull && kept < POST) {
          int r = __builtin_ctzll(alive);
          if (lane == 0) lds.nms.keeplist[kept] = cc * 64 + r;
          kept++;
          u64 sup = rl64(diag[cc], r);     // row's in-chunk suppression word
          alive &= ~sup;
          alive &= ~(1ull << r);
        }
        int nc = kept - kept0;
        if (nc > 0 && kept < POST && cc < 15) {
          u64 part = 0;
          for (int j = g; j < nc; j += 4) {
            int row = lds.nms.keeplist[kept0 + j];
            part |= (row < LDSROWS) ? lds.nms.smask[row * 16 + w]
                                    : M[(size_t)row * 16 + w];
          }
          part |= sx64(part, 16);
          part |= sx64(part, 32);
          rem |= part;                     // only lanes <16 meaningful
        }
        if (kept >= POST) break;
      }
      if (lane == 0) lds.nms.kept = kept;
    }
    __syncthreads();
    for (int o = tid; o < POST; o += 256) {
      float4 bx = make_float4(0.f, 0.f, 0.f, 0.f);
      float  sc = 0.f;
      if (o < lds.nms.kept) {
        int i2 = lds.nms.keeplist[o];
        bx = boxes[img * PRE + i2];
        sc = scores[img * PRE + i2];
      }
      float* op = out + ((size_t)img * POST + o) * 5;
      op[0] = bx.x; op[1] = bx.y; op[2] = bx.z; op[3] = bx.w; op[4] = sc;
    }
  }
}

// ================== FALLBACK: original 7-dispatch path ==================

__global__ __launch_bounds__(256) void k_hist(const float* __restrict__ logits,
                                              u32* __restrict__ rhist) {
  __shared__ u32 h[NBIN];
  const int img = blockIdx.y, c = blockIdx.x;
  for (int i = threadIdx.x; i < NBIN; i += 256) h[i] = 0;
  __syncthreads();
  const float4* L = (const float4*)(logits + (size_t)img * NPI) + (size_t)c * F4PB_H;
  for (int i = threadIdx.x; i < F4PB_H; i += 256) {
    float4 v = L[i];
    atomicAdd(&h[fkey(v.x) >> KSHIFT], 1u);
    atomicAdd(&h[fkey(v.y) >> KSHIFT], 1u);
    atomicAdd(&h[fkey(v.z) >> KSHIFT], 1u);
    atomicAdd(&h[fkey(v.w) >> KSHIFT], 1u);
  }
  __syncthreads();
  u32* R = rhist + img * NBIN;
  for (int i = threadIdx.x; i < NBIN; i += 256) {
    u32 cn = h[i];
    if (cn) atomicAdd(&R[i], cn);
  }
}

__global__ __launch_bounds__(1024) void k_select(const u32* __restrict__ rhist,
                                                 int* __restrict__ thresh) {
  const int img = blockIdx.x;
  const int t = threadIdx.x;
  const int lane = t & 63, w = t >> 6;
  const uint4* H4 = (const uint4*)(rhist + img * NBIN);
  uint4 v0 = H4[2 * t], v1 = H4[2 * t + 1];
  u32 binc[8] = {v0.x, v0.y, v0.z, v0.w, v1.x, v1.y, v1.z, v1.w};
  u32 s = 0;
#pragma unroll
  for (int b = 0; b < 8; b++) s += binc[b];
  u32 suf = s;
#pragma unroll
  for (int off = 1; off < 64; off <<= 1) {
    u32 o = (u32)__shfl_down((int)suf, off, 64);
    if (lane + off < 64) suf += o;
  }
  __shared__ u32 wtot[16];
  if (lane == 0) wtot[w] = suf;
  __syncthreads();
  u32 wsuf = 0;
  for (int ww = w + 1; ww < 16; ww++) wsuf += wtot[ww];
  u32 suffix_incl = suf + wsuf;
  u32 s_excl = suffix_incl - s;
  if (suffix_incl >= (u32)PRE && s_excl < (u32)PRE) {
    u32 cum = s_excl;
    int bin = 8 * t;
#pragma unroll
    for (int b = 7; b >= 0; b--) {
      cum += binc[b];
      if (cum >= (u32)PRE) { bin = 8 * t + b; break; }
    }
    thresh[img] = bin;
  }
}

__global__ __launch_bounds__(256) void k_compact(const float* __restrict__ logits,
                                                 const int* __restrict__ thresh,
                                                 u32* __restrict__ cnt,
                                                 u64* __restrict__ cand) {
  __shared__ u64 buf[LBUF];
  __shared__ u32 bcnt;
  __shared__ u32 gbase;
  const int img = blockIdx.y, c = blockIdx.x;
  const int tb  = thresh[img];
  if (threadIdx.x == 0) bcnt = 0;
  __syncthreads();
  const float4* L = (const float4*)(logits + (size_t)img * NPI) + (size_t)c * F4PB_C;
  const int ebase = c * EPB_C;
  for (int i = threadIdx.x; i < F4PB_C; i += 256) {
    float4 v = L[i];
    float xs[4] = {v.x, v.y, v.z, v.w};
#pragma unroll
    for (int q = 0; q < 4; q++) {
      float x = xs[q];
      if ((int)(fkey(x) >> KSHIFT) >= tb) {
        float ef = (float)exp(-(double)x);
        float sg = 1.0f / (1.0f + ef);
        u32 e = (u32)(ebase + 4 * i + q);
        u32 p = atomicAdd(&bcnt, 1u);
        if (p < LBUF)
          buf[p] = ((u64)fkey(sg) << 32) | (u64)(0xFFFFFFFFu - e);
      }
    }
  }
  __syncthreads();
  if (threadIdx.x == 0) {
    u32 m = bcnt < LBUF ? bcnt : LBUF;
    bcnt = m;
    gbase = atomicAdd(&cnt[img], m);
  }
  __syncthreads();
  const u32 m = bcnt, gb = gbase;
  for (u32 j = threadIdx.x; j < m; j += 256) {
    u32 pos = gb + j;
    if (pos < CAP) cand[img * CAP + pos] = buf[j];
  }
}

#define RB 8
__global__ __launch_bounds__(256) void k_rank(
    const float* __restrict__ deltas, const float* __restrict__ anchors,
    const u32* __restrict__ cnt, const u64* __restrict__ cand,
    float4* __restrict__ boxes, float* __restrict__ scores, u64* __restrict__ validw) {
  __shared__ u64 skey[CAP];
  const int img = blockIdx.y;
  int n = (int)cnt[img];
  if (n > CAP) n = CAP;
  for (int i = threadIdx.x; i < n; i += 256) skey[i] = cand[img * CAP + i];
  __syncthreads();
  const int r0 = blockIdx.x * 256 + threadIdx.x;
  const int r1 = r0 + RB * 256;
  u64 k0 = (r0 < n) ? skey[r0] : 0ull;
  u64 k1 = (r1 < n) ? skey[r1] : 0ull;
  int c0 = 0, c1 = 0;
  for (int j = 0; j < n; j++) {
    u64 kj = skey[j];
    c0 += (kj > k0);
    c1 += (kj > k1);
  }
  if (r0 < n && c0 < PRE) emit_row(img, c0, k0, deltas, anchors, boxes, scores, validw);
  if (r1 < n && c1 < PRE) emit_row(img, c1, k1, deltas, anchors, boxes, scores, validw);
}

__global__ __launch_bounds__(1024) void k_iou(const float4* __restrict__ boxes,
                                              u64* __restrict__ mask) {
  __shared__ float4 sb[1024];
  __shared__ float  sa[1024];
  const int img = blockIdx.y;
  const int tid = threadIdx.x;
  {
    float4 b = (tid < PRE) ? boxes[img * PRE + tid]
                           : make_float4(0.f, 0.f, 0.f, 0.f);
    sb[tid] = b;
    sa[tid] = (b.z - b.x) * (b.w - b.y);
  }
  __syncthreads();
  const int lane = tid & 63;
  const int wv   = tid >> 6;
  const int i    = blockIdx.x * 64 + lane;
  const bool rowok = (i < PRE);
  const float4 bi = sb[blockIdx.x * 64 + lane];
  const float  ai = sa[blockIdx.x * 64 + lane];
  const int cbase = wv << 6;
  u64 bits = 0;
#pragma unroll
  for (int k = 0; k < 64; k++) {
    int c = cbase + k;
    float4 bc = sb[c];
    float ac  = sa[c];
    float ltx = fmaxf(bi.x, bc.x), lty = fmaxf(bi.y, bc.y);
    float rbx = fminf(bi.z, bc.z), rby = fminf(bi.w, bc.w);
    float iw = fmaxf(rbx - ltx, 0.f), ih = fmaxf(rby - lty, 0.f);
    float inter = iw * ih;
    float iou = inter / (ai + ac - inter + 1e-9f);
    bits |= (iou > NMSF) ? (1ull << k) : 0ull;
  }
  int d = i - cbase;
  u64 gtmask = (d < 0) ? ~0ull : ((d >= 63) ? 0ull : (~0ull << (d + 1)));
  int rem = PRE - cbase;
  u64 tmask = (rem >= 64) ? ~0ull : ((rem <= 0) ? 0ull : ((1ull << rem) - 1ull));
  bits &= gtmask & tmask;
  if (rowok) mask[((size_t)img * PRE + i) * 16 + wv] = bits;
}

__global__ __launch_bounds__(NMS_T) void k_nms(
    const u64* __restrict__ mask, const u64* __restrict__ validw,
    const float4* __restrict__ boxes, const float* __restrict__ scores,
    float* __restrict__ out) {
  __shared__ u64 smask[LDSROWS * 16];
  __shared__ int skeeplist[POST];
  __shared__ int skept;
  const int img = blockIdx.x;
  const int tid = threadIdx.x;
  const u64* M = mask + (size_t)img * PRE * 16;
  u64 diag[16];
  if (tid < 64) {
#pragma unroll
    for (int cc = 0; cc < 16; cc++) {
      int row = cc * 64 + tid;
      diag[cc] = (row < PRE) ? M[(size_t)row * 16 + cc] : 0ull;
    }
  }
  for (int e = tid; e < LDSROWS * 16; e += NMS_T) smask[e] = M[e];
  __syncthreads();
  if (tid < 64) {
    const int lane = tid;
    const int w = lane & 15, g = lane >> 4;
    u64 rem = ~0ull;
    if (lane < 16) {
      rem = ~validw[img * 16 + lane];
      if (lane == 15) rem |= 0xFFFFFF0000000000ull;
    }
    int kept = 0;
#pragma unroll
    for (int cc = 0; cc < 16; cc++) {
      u64 alive = ~rl64(rem, cc);
      int kept0 = kept;
      while (alive != 0ull && kept < POST) {
        int r = __builtin_ctzll(alive);
        if (lane == 0) skeeplist[kept] = cc * 64 + r;
        kept++;
        u64 sup = rl64(diag[cc], r);
        alive &= ~sup;
        alive &= ~(1ull << r);
      }
      int nc = kept - kept0;
      if (nc > 0 && kept < POST && cc < 15) {
        u64 part = 0;
        for (int j = g; j < nc; j += 4) {
          int row = skeeplist[kept0 + j];
          part |= (row < LDSROWS) ? smask[row * 16 + w] : M[(size_t)row * 16 + w];
        }
        part |= sx64(part, 16);
        part |= sx64(part, 32);
        rem |= part;
      }
      if (kept >= POST) break;
    }
    if (lane == 0) skept = kept;
  }
  __syncthreads();
  if (tid < POST) {
    float4 bx = make_float4(0.f, 0.f, 0.f, 0.f);
    float  sc = 0.f;
    if (tid < skept) {
      int i = skeeplist[tid];
      bx = boxes[img * PRE + i];
      sc = scores[img * PRE + i];
    }
    float* o = out + ((size_t)img * POST + tid) * 5;
    o[0] = bx.x; o[1] = bx.y; o[2] = bx.z; o[3] = bx.w; o[4] = sc;
  }
}

extern "C" void kernel_launch(void* const* d_in, const int* in_sizes, int n_in,
                              void* d_out, int out_size, void* d_ws, size_t ws_size,
                              hipStream_t stream) {
  const float* logits  = (const float*)d_in[0];
  const float* deltas  = (const float*)d_in[1];
  const float* anchors = (const float*)d_in[2];
  float* out = (float*)d_out;
  char* ws = (char*)d_ws;

  u32* cnt      = (u32*)(ws + CNT_OFF);
  int* thresh   = (int*)(ws + THRESH_OFF);
  u64* validw   = (u64*)(ws + VALID_OFF);
  u32* rhist    = (u32*)(ws + RHIST_OFF);
  float4* boxes = (float4*)(ws + BOX_OFF);
  float* scores = (float*)(ws + SCORE_OFF);
  u64* cand     = (u64*)(ws + CAND_OFF);
  u64* mask     = (u64*)(ws + MASK_OFF);

  void* args[] = {(void*)&logits, (void*)&deltas, (void*)&anchors,
                  (void*)&cnt, (void*)&thresh, (void*)&validw, (void*)&rhist,
                  (void*)&boxes, (void*)&scores, (void*)&cand, (void*)&mask,
                  (void*)&out};
  hipError_t err = hipLaunchCooperativeKernel((void*)k_fused, dim3(FGRID), dim3(256),
                                              args, 0, stream);
  if (err != hipSuccess) {
    // fallback: proven 7-dispatch path (210 us)
    hipMemsetAsync(ws, 0, ZERO_BYTES, stream);
    dim3 gh(CHUNK_H, B_IMG);
    k_hist<<<gh, 256, 0, stream>>>(logits, rhist);
    k_select<<<B_IMG, 1024, 0, stream>>>(rhist, thresh);
    dim3 gc(CHUNK_C, B_IMG);
    k_compact<<<gc, 256, 0, stream>>>(logits, thresh, cnt, cand);
    dim3 gr(RB, B_IMG);
    k_rank<<<gr, 256, 0, stream>>>(deltas, anchors, cnt, cand, boxes, scores, validw);
    dim3 g2(16, B_IMG);
    k_iou<<<g2, 1024, 0, stream>>>(boxes, mask);
    k_nms<<<B_IMG, NMS_T, 0, stream>>>(mask, validw, boxes, scores, out);
  }
}

// Round 2
// 207.078 us; speedup vs baseline: 2.3456x; 2.3456x over previous
//
#include <hip/hip_runtime.h>
#include <stdint.h>
#include <math.h>

typedef unsigned long long u64;
typedef unsigned int u32;

#define NPI   360000
#define B_IMG 8
#define PRE   1000
#define POST  300
#define CAP   4096
#define NMSF  0.7f
#define IMG_W 800.0f
#define IMG_H 800.0f

#define NBIN    4096          // 12-bit sortable-key histogram
#define KSHIFT  20            // fkey >> 20 -> 12-bit bin
#define NGRP    64            // coarse groups (64 bins each)
#define CHUNK_H 30            // hist blocks per image (divides 90000)
#define F4PB_H  (NPI / 4 / CHUNK_H)   // 3000
#define CHUNK_C 48            // compact blocks per image
#define F4PB_C  (NPI / 4 / CHUNK_C)   // 1875
#define EPB_C   (NPI / CHUNK_C)       // 7500
#define LBUF    1024          // per-block candidate buffer

// ---- workspace layout (bytes) ----
#define CNT_OFF     0                 // 8*4 = 32
#define VALID_OFF   256               // 8*16*8 = 1024          -> 1280
#define PHIST_OFF   4096              // 8*30*4096*4 = 3932160  -> 3936256
#define PCOARSE_OFF 3936256           // 8*30*64*4   = 61440    -> 3997696
#define BOX_OFF     3997696           // 8*1000*16   = 128000   -> 4125696
#define SCORE_OFF   4125696           // 8*1000*4    = 32000    -> 4157696
#define CAND_OFF    4157696           // 8*4096*8    = 262144   -> 4419840
#define MASK_OFF    4419840           // 8*1000*16*8 = 1024000  -> 5443840

#define LDSROWS 496
#define NMS_T   320

__device__ __forceinline__ u32 fkey(float f) {
  u32 u = __float_as_uint(f);
  return (u & 0x80000000u) ? ~u : (u | 0x80000000u);  // ascending-order bits
}
__device__ __forceinline__ u64 rl64(u64 v, int lane) {
  u32 lo = (u32)__builtin_amdgcn_readlane((int)(u32)v, lane);
  u32 hi = (u32)__builtin_amdgcn_readlane((int)(u32)(v >> 32), lane);
  return ((u64)hi << 32) | lo;
}
__device__ __forceinline__ u64 sx64(u64 v, int m) {
  u32 lo = (u32)__shfl_xor((int)(u32)v, m, 64);
  u32 hi = (u32)__shfl_xor((int)(u32)(v >> 32), m, 64);
  return ((u64)hi << 32) | lo;
}

// ---- K1: per-(image,chunk) LDS histogram -> private slot (no atomics, no pre-zero)
//      also emits 64-group coarse sums and zeroes cnt/validw for later stages ----
__global__ __launch_bounds__(256) void k_hist(const float* __restrict__ logits,
                                              u32* __restrict__ phist,
                                              u32* __restrict__ pcoarse,
                                              u32* __restrict__ cnt,
                                              u64* __restrict__ validw) {
  __shared__ u32 h[NBIN];
  const int img = blockIdx.y, c = blockIdx.x;
  const int tid = threadIdx.x;
  for (int i = tid; i < NBIN; i += 256) h[i] = 0;
  __syncthreads();
  const float4* L = (const float4*)(logits + (size_t)img * NPI) + (size_t)c * F4PB_H;
  for (int i = tid; i < F4PB_H; i += 256) {
    float4 v = L[i];
    atomicAdd(&h[fkey(v.x) >> KSHIFT], 1u);
    atomicAdd(&h[fkey(v.y) >> KSHIFT], 1u);
    atomicAdd(&h[fkey(v.z) >> KSHIFT], 1u);
    atomicAdd(&h[fkey(v.w) >> KSHIFT], 1u);
  }
  __syncthreads();
  // write fine partial hist (coalesced streaming store, no atomics)
  u32* P = phist + ((size_t)img * CHUNK_H + c) * NBIN;
  for (int i = tid; i < NBIN; i += 256) P[i] = h[i];
  // coarse 64-group sums
  if (tid < NGRP) {
    u32 s = 0;
#pragma unroll
    for (int b = 0; b < NBIN / NGRP; b++) s += h[tid * (NBIN / NGRP) + b];
    pcoarse[((size_t)img * CHUNK_H + c) * NGRP + tid] = s;
  }
  // zero accumulators consumed by later dispatches (hist completes first)
  if (c == 0) {
    if (tid < 16) validw[img * 16 + tid] = 0;
    if (img == 0 && tid < B_IMG) cnt[tid] = 0;
  }
}

// ---- K2: compact candidates >= threshold; threshold computed in-block via
//      two-level (coarse group -> fine bin) suffix scan over partial hists ----
__global__ __launch_bounds__(256) void k_compact(const float* __restrict__ logits,
                                                 const u32* __restrict__ phist,
                                                 const u32* __restrict__ pcoarse,
                                                 u32* __restrict__ cnt,
                                                 u64* __restrict__ cand) {
  __shared__ u64 buf[LBUF];
  __shared__ u32 bcnt;
  __shared__ u32 gbase;
  __shared__ int stb;
  const int img = blockIdx.y, c = blockIdx.x;
  const int t = threadIdx.x;
  if (t == 0) { bcnt = 0; stb = 0; }
  // ---- inline select (wave 0 only) ----
  if (t < 64) {
    // coarse: group totals over chunks
    const u32* PC = pcoarse + (size_t)img * CHUNK_H * NGRP;
    u32 cg = 0;
    for (int cc = 0; cc < CHUNK_H; cc++) cg += PC[cc * NGRP + t];
    // inclusive suffix sum across 64 groups (lane t -> count in groups >= t)
    u32 suf = cg;
#pragma unroll
    for (int off = 1; off < 64; off <<= 1) {
      u32 o = (u32)__shfl_down((int)suf, off, 64);
      if (t + off < 64) suf += o;
    }
    u32 sx = suf - cg;                       // count in groups > t
    u64 bal = __ballot(suf >= (u32)PRE && sx < (u32)PRE);
    if (bal) {                               // total >= PRE: crossing group exists
      int gc = __builtin_ctzll(bal);
      u32 s_above = (u32)__shfl((int)sx, gc, 64);   // count in groups > gc
      // fine: bin totals within group gc
      const u32* P = phist + (size_t)img * CHUNK_H * NBIN + gc * (NBIN / NGRP);
      u32 fb = 0;
      for (int cc = 0; cc < CHUNK_H; cc++) fb += P[(size_t)cc * NBIN + t];
      u32 fsuf = fb;
#pragma unroll
      for (int off = 1; off < 64; off <<= 1) {
        u32 o = (u32)__shfl_down((int)fsuf, off, 64);
        if (t + off < 64) fsuf += o;
      }
      u32 fincl = fsuf + s_above;            // count(key-bin >= gc*64+t)
      u32 fexcl = fincl - fb;
      if (fincl >= (u32)PRE && fexcl < (u32)PRE) stb = gc * (NBIN / NGRP) + t;
    }
  }
  __syncthreads();
  const int tb = stb;
  // ---- compact pass ----
  const float4* L = (const float4*)(logits + (size_t)img * NPI) + (size_t)c * F4PB_C;
  const int ebase = c * EPB_C;
  for (int i = t; i < F4PB_C; i += 256) {
    float4 v = L[i];
    float xs[4] = {v.x, v.y, v.z, v.w};
#pragma unroll
    for (int q = 0; q < 4; q++) {
      float x = xs[q];
      if ((int)(fkey(x) >> KSHIFT) >= tb) {
        // fp32 sigmoid with correctly-rounded exp: replicates numpy f32
        // tie structure exactly (verified: absmax 0.0)
        float ef = (float)exp(-(double)x);
        float sg = 1.0f / (1.0f + ef);
        u32 e = (u32)(ebase + 4 * i + q);
        u32 p = atomicAdd(&bcnt, 1u);
        if (p < LBUF)
          buf[p] = ((u64)fkey(sg) << 32) | (u64)(0xFFFFFFFFu - e);
      }
    }
  }
  __syncthreads();
  if (t == 0) {
    u32 m = bcnt < LBUF ? bcnt : LBUF;
    bcnt = m;
    gbase = atomicAdd(&cnt[img], m);
  }
  __syncthreads();
  const u32 m = bcnt, gb = gbase;
  for (u32 j = t; j < m; j += 256) {
    u32 pos = gb + j;
    if (pos < CAP) cand[img * CAP + pos] = buf[j];
  }
}

// ---- K3: exact rank (keys unique: idx embedded) + decode/clip, no sort ----
__device__ __forceinline__ void emit_row(
    int img, int row, u64 key,
    const float* __restrict__ deltas, const float* __restrict__ anchors,
    float4* __restrict__ boxes, float* __restrict__ scores, u64* __restrict__ validw) {
  u32 hi  = (u32)(key >> 32);
  u32 idx = 0xFFFFFFFFu - (u32)(key & 0xFFFFFFFFu);
  u32 su  = (hi & 0x80000000u) ? (hi ^ 0x80000000u) : ~hi;
  float sc = __uint_as_float(su);
  size_t off = (size_t)img * NPI + idx;
  float4 d = ((const float4*)deltas)[off];
  float4 a = ((const float4*)anchors)[off];
  float aw = a.z - a.x, ah = a.w - a.y;
  float acx = a.x + 0.5f * aw, acy = a.y + 0.5f * ah;
  float cx = d.x * aw + acx, cy = d.y * ah + acy;
  float w = expf(d.z) * aw, h = expf(d.w) * ah;
  float x1 = cx - 0.5f * w, y1 = cy - 0.5f * h;
  float x2 = cx + 0.5f * w, y2 = cy + 0.5f * h;
  x1 = fminf(fmaxf(x1, 0.f), IMG_W);
  y1 = fminf(fmaxf(y1, 0.f), IMG_H);
  x2 = fminf(fmaxf(x2, 0.f), IMG_W);
  y2 = fminf(fmaxf(y2, 0.f), IMG_H);
  boxes[img * PRE + row]  = make_float4(x1, y1, x2, y2);
  scores[img * PRE + row] = sc;
  if (((x2 - x1) >= 1e-3f) && ((y2 - y1) >= 1e-3f))
    atomicOr(&validw[img * 16 + (row >> 6)], 1ull << (row & 63));
}

#define RB 8
__global__ __launch_bounds__(256) void k_rank(
    const float* __restrict__ deltas, const float* __restrict__ anchors,
    const u32* __restrict__ cnt, const u64* __restrict__ cand,
    float4* __restrict__ boxes, float* __restrict__ scores, u64* __restrict__ validw) {
  __shared__ u64 skey[CAP];
  const int img = blockIdx.y;
  int n = (int)cnt[img];
  if (n > CAP) n = CAP;
  for (int i = threadIdx.x; i < n; i += 256) skey[i] = cand[img * CAP + i];
  __syncthreads();
  const int r0 = blockIdx.x * 256 + threadIdx.x;
  const int r1 = r0 + RB * 256;
  u64 k0 = (r0 < n) ? skey[r0] : 0ull;
  u64 k1 = (r1 < n) ? skey[r1] : 0ull;
  int c0 = 0, c1 = 0;
  for (int j = 0; j < n; j++) {
    u64 kj = skey[j];           // same address across lanes -> LDS broadcast
    c0 += (kj > k0);
    c1 += (kj > k1);
  }
  if (r0 < n && c0 < PRE) emit_row(img, c0, k0, deltas, anchors, boxes, scores, validw);
  if (r1 < n && c1 < PRE) emit_row(img, c1, k1, deltas, anchors, boxes, scores, validw);
}

// ---- K4: suppression bitmask via LDS broadcast (zero bank conflicts) ----
__global__ __launch_bounds__(1024) void k_iou(const float4* __restrict__ boxes,
                                              u64* __restrict__ mask) {
  __shared__ float4 sb[1024];
  __shared__ float  sa[1024];
  const int img = blockIdx.y;
  const int tid = threadIdx.x;
  {
    float4 b = (tid < PRE) ? boxes[img * PRE + tid]
                           : make_float4(0.f, 0.f, 0.f, 0.f);
    sb[tid] = b;
    sa[tid] = (b.z - b.x) * (b.w - b.y);
  }
  __syncthreads();
  const int lane = tid & 63;
  const int wv   = tid >> 6;          // word index 0..15
  const int i    = blockIdx.x * 64 + lane;   // row
  const bool rowok = (i < PRE);
  const float4 bi = sb[blockIdx.x * 64 + lane];
  const float  ai = sa[blockIdx.x * 64 + lane];
  const int cbase = wv << 6;
  u64 bits = 0;
#pragma unroll
  for (int k = 0; k < 64; k++) {
    int c = cbase + k;
    float4 bc = sb[c];                // broadcast read
    float ac  = sa[c];
    float ltx = fmaxf(bi.x, bc.x), lty = fmaxf(bi.y, bc.y);
    float rbx = fminf(bi.z, bc.z), rby = fminf(bi.w, bc.w);
    float iw = fmaxf(rbx - ltx, 0.f), ih = fmaxf(rby - lty, 0.f);
    float inter = iw * ih;
    float iou = inter / (ai + ac - inter + 1e-9f);  // IEEE div, matches ref
    bits |= (iou > NMSF) ? (1ull << k) : 0ull;
  }
  int d = i - cbase;
  u64 gtmask = (d < 0) ? ~0ull : ((d >= 63) ? 0ull : (~0ull << (d + 1)));
  int rem = PRE - cbase;
  u64 tmask = (rem >= 64) ? ~0ull : ((rem <= 0) ? 0ull : ((1ull << rem) - 1ull));
  bits &= gtmask & tmask;
  if (rowok) mask[((size_t)img * PRE + i) * 16 + wv] = bits;
}

// ---- K5: chunked greedy scan — scalar in-chunk decisions via readlane ----
__global__ __launch_bounds__(NMS_T) void k_nms(
    const u64* __restrict__ mask, const u64* __restrict__ validw,
    const float4* __restrict__ boxes, const float* __restrict__ scores,
    float* __restrict__ out) {
  __shared__ u64 smask[LDSROWS * 16];
  __shared__ int skeeplist[POST];
  __shared__ int skept;
  const int img = blockIdx.x;
  const int tid = threadIdx.x;
  const u64* M = mask + (size_t)img * PRE * 16;
  u64 diag[16];
  if (tid < 64) {
#pragma unroll
    for (int cc = 0; cc < 16; cc++) {
      int row = cc * 64 + tid;
      diag[cc] = (row < PRE) ? M[(size_t)row * 16 + cc] : 0ull;
    }
  }
  for (int e = tid; e < LDSROWS * 16; e += NMS_T) smask[e] = M[e];
  __syncthreads();
  if (tid < 64) {
    const int lane = tid;
    const int w = lane & 15, g = lane >> 4;
    u64 rem = ~0ull;
    if (lane < 16) {
      rem = ~validw[img * 16 + lane];
      if (lane == 15) rem |= 0xFFFFFF0000000000ull;  // rows 1000..1023 invalid
    }
    int kept = 0;
#pragma unroll
    for (int cc = 0; cc < 16; cc++) {
      u64 alive = ~rl64(rem, cc);      // wave-uniform
      int kept0 = kept;
      while (alive != 0ull && kept < POST) {
        int r = __builtin_ctzll(alive);
        if (lane == 0) skeeplist[kept] = cc * 64 + r;
        kept++;
        u64 sup = rl64(diag[cc], r);   // row's in-chunk suppression word
        alive &= ~sup;
        alive &= ~(1ull << r);
      }
      int nc = kept - kept0;
      if (nc > 0 && kept < POST && cc < 15) {
        u64 part = 0;
        for (int j = g; j < nc; j += 4) {
          int row = skeeplist[kept0 + j];
          part |= (row < LDSROWS) ? smask[row * 16 + w] : M[(size_t)row * 16 + w];
        }
        part |= sx64(part, 16);
        part |= sx64(part, 32);
        rem |= part;                   // only lanes <16 meaningful
      }
      if (kept >= POST) break;
    }
    if (lane == 0) skept = kept;
  }
  __syncthreads();
  if (tid < POST) {
    float4 bx = make_float4(0.f, 0.f, 0.f, 0.f);
    float  sc = 0.f;
    if (tid < skept) {
      int i = skeeplist[tid];
      bx = boxes[img * PRE + i];
      sc = scores[img * PRE + i];
    }
    float* o = out + ((size_t)img * POST + tid) * 5;
    o[0] = bx.x; o[1] = bx.y; o[2] = bx.z; o[3] = bx.w; o[4] = sc;
  }
}

extern "C" void kernel_launch(void* const* d_in, const int* in_sizes, int n_in,
                              void* d_out, int out_size, void* d_ws, size_t ws_size,
                              hipStream_t stream) {
  const float* logits  = (const float*)d_in[0];
  const float* deltas  = (const float*)d_in[1];
  const float* anchors = (const float*)d_in[2];
  float* out = (float*)d_out;
  char* ws = (char*)d_ws;

  u32* cnt      = (u32*)(ws + CNT_OFF);
  u64* validw   = (u64*)(ws + VALID_OFF);
  u32* phist    = (u32*)(ws + PHIST_OFF);
  u32* pcoarse  = (u32*)(ws + PCOARSE_OFF);
  float4* boxes = (float4*)(ws + BOX_OFF);
  float* scores = (float*)(ws + SCORE_OFF);
  u64* cand     = (u64*)(ws + CAND_OFF);
  u64* mask     = (u64*)(ws + MASK_OFF);

  dim3 gh(CHUNK_H, B_IMG);
  k_hist<<<gh, 256, 0, stream>>>(logits, phist, pcoarse, cnt, validw);
  dim3 gc(CHUNK_C, B_IMG);
  k_compact<<<gc, 256, 0, stream>>>(logits, phist, pcoarse, cnt, cand);
  dim3 gr(RB, B_IMG);
  k_rank<<<gr, 256, 0, stream>>>(deltas, anchors, cnt, cand, boxes, scores, validw);
  dim3 g2(16, B_IMG);
  k_iou<<<g2, 1024, 0, stream>>>(boxes, mask);
  k_nms<<<B_IMG, NMS_T, 0, stream>>>(mask, validw, boxes, scores, out);
}